// Round 4
// baseline (3428.748 us; speedup 1.0000x reference)
//
#include <hip/hip_runtime.h>
#include <math.h>

#define BATCH 32
#define TFRAMES 1024
#define NBINS 257
#define HOP 160
#define LOUT 163680
#define XPLEN 164192
#define NITER 32
#define BSTRIDE 1280              // 8 frames * HOP per block
#define HALO 352                  // NFFT - HOP
#define SPAN (BSTRIDE+HALO)       // 1632 floats per-block OLA span
#define NBLK 128                  // blocks per batch row
#define SLOT SPAN
#define SB ((size_t)NBLK*SLOT)
#define SBUF ((size_t)BATCH*SB)
#define GSTRIDE 264               // float2 stride of per-frame LDS sub-buffer

// 16 complex values per lane in ext-vectors. CRITICAL (rule #20, r2/r3
// post-mortem): every subscript below is a compile-time LITERAL via
// macro expansion -- a loop-variable subscript (even under #pragma
// unroll) makes clang alloca the vector -> 109 MB/dispatch scratch.
typedef float f16v __attribute__((ext_vector_type(16)));

#define REP16(OP) OP(0) OP(1) OP(2) OP(3) OP(4) OP(5) OP(6) OP(7) \
                  OP(8) OP(9) OP(10) OP(11) OP(12) OP(13) OP(14) OP(15)
#define REP15(OP) OP(1) OP(2) OP(3) OP(4) OP(5) OP(6) OP(7) \
                  OP(8) OP(9) OP(10) OP(11) OP(12) OP(13) OP(14) OP(15)

__device__ __forceinline__ float cosr(float x){ return __builtin_amdgcn_cosf(x); }
__device__ __forceinline__ float sinr(float x){ return __builtin_amdgcn_sinf(x); }
__device__ __forceinline__ void wsync(){
    __builtin_amdgcn_fence(__ATOMIC_SEQ_CST, "wavefront");
    __builtin_amdgcn_wave_barrier();
}
__device__ __forceinline__ float bperm(int addr, float v){
    return __int_as_float(__builtin_amdgcn_ds_bpermute(addr, __float_as_int(v)));
}

// radix-4 butterfly on scalars
template<int SIGN>
__device__ __forceinline__ void bfly4s(float x0r,float x0i,float x1r,float x1i,
                                       float x2r,float x2i,float x3r,float x3i,
                                       float&y0r,float&y0i,float&y1r,float&y1i,
                                       float&y2r,float&y2i,float&y3r,float&y3i){
    constexpr float SG = (SIGN>0)?1.f:-1.f;
    float apc_r=x0r+x2r, apc_i=x0i+x2i;
    float amc_r=x0r-x2r, amc_i=x0i-x2i;
    float bpd_r=x1r+x3r, bpd_i=x1i+x3i;
    float bmd_r=x1r-x3r, bmd_i=x1i-x3i;
    y0r=apc_r+bpd_r; y0i=apc_i+bpd_i;
    y2r=apc_r-bpd_r; y2i=apc_i-bpd_i;
    y1r=amc_r-SG*bmd_i; y1i=amc_i+SG*bmd_r;
    y3r=amc_r+SG*bmd_i; y3i=amc_i-SG*bmd_r;
}

// multiply by W16^{SIGN*J}; J compile-time
template<int SIGN, int JJ>
__device__ __forceinline__ void tw16(float& vr, float& vi){
    constexpr float SG = (SIGN>0)?1.f:-1.f;
    constexpr int J = JJ & 15;
    constexpr float CT16[16] = { 1.f, 0.9238795325f, 0.7071067812f, 0.3826834324f,
                                 0.f,-0.3826834324f,-0.7071067812f,-0.9238795325f,
                                -1.f,-0.9238795325f,-0.7071067812f,-0.3826834324f,
                                 0.f, 0.3826834324f, 0.7071067812f, 0.9238795325f};
    constexpr float ST16[16] = { 0.f, 0.3826834324f, 0.7071067812f, 0.9238795325f,
                                 1.f, 0.9238795325f, 0.7071067812f, 0.3826834324f,
                                 0.f,-0.3826834324f,-0.7071067812f,-0.9238795325f,
                                -1.f,-0.9238795325f,-0.7071067812f,-0.3826834324f};
    if constexpr (J==4){ float tv=vr; vr=-SG*vi; vi=SG*tv; }
    else if constexpr (J!=0){
        float tr2 = CT16[J]*vr - SG*ST16[J]*vi;
        vi        = CT16[J]*vi + SG*ST16[J]*vr;
        vr = tr2;
    }
}

// stage 1 of 16-pt DFT, input digit BQ (all literal indices)
template<int SIGN, int BQ>
__device__ __forceinline__ void fft16_s1(const f16v& zr, const f16v& zi,
                                         f16v& ur, f16v& ui){
    float y0r,y0i,y1r,y1i,y2r,y2i,y3r,y3i;
    bfly4s<SIGN>(zr[BQ],zi[BQ], zr[BQ+4],zi[BQ+4],
                 zr[BQ+8],zi[BQ+8], zr[BQ+12],zi[BQ+12],
                 y0r,y0i,y1r,y1i,y2r,y2i,y3r,y3i);
    tw16<SIGN, BQ  >(y1r,y1i);
    tw16<SIGN, 2*BQ>(y2r,y2i);
    tw16<SIGN, 3*BQ>(y3r,y3i);
    ur[BQ]   =y0r; ui[BQ]   =y0i;
    ur[4+BQ] =y1r; ui[4+BQ] =y1i;
    ur[8+BQ] =y2r; ui[8+BQ] =y2i;
    ur[12+BQ]=y3r; ui[12+BQ]=y3i;
}

// stage 2: radix-4, output k = C + 4d (all literal indices)
template<int SIGN, int C>
__device__ __forceinline__ void fft16_s2(const f16v& ur, const f16v& ui,
                                         f16v& zr, f16v& zi){
    float y0r,y0i,y1r,y1i,y2r,y2i,y3r,y3i;
    bfly4s<SIGN>(ur[4*C],ui[4*C], ur[4*C+1],ui[4*C+1],
                 ur[4*C+2],ui[4*C+2], ur[4*C+3],ui[4*C+3],
                 y0r,y0i,y1r,y1i,y2r,y2i,y3r,y3i);
    zr[C]   =y0r; zi[C]   =y0i;
    zr[C+4] =y1r; zi[C+4] =y1i;
    zr[C+8] =y2r; zi[C+8] =y2i;
    zr[C+12]=y3r; zi[C+12]=y3i;
}

template<int SIGN>
__device__ __forceinline__ void fft16v(f16v& zr, f16v& zi){
    f16v ur, ui;
    fft16_s1<SIGN,0>(zr,zi,ur,ui);
    fft16_s1<SIGN,1>(zr,zi,ur,ui);
    fft16_s1<SIGN,2>(zr,zi,ur,ui);
    fft16_s1<SIGN,3>(zr,zi,ur,ui);
    fft16_s2<SIGN,0>(ur,ui,zr,zi);
    fft16_s2<SIGN,1>(ur,ui,zr,zi);
    fft16_s2<SIGN,2>(ur,ui,zr,zi);
    fft16_s2<SIGN,3>(ur,ui,zr,zi);
}

// 256-pt FFT per 16-lane group. In: n = 16*reg + (lane&15).
// Out: k = (lane&15) + 16*reg. tb: 264-float2 LDS sub-buffer.
template<int SIGN>
__device__ __forceinline__ void fft256v(f16v& zr, f16v& zi,
                                        float2* __restrict__ tb, int k1l){
    constexpr float SG = (SIGN>0)?1.f:-1.f;
    fft16v<SIGN>(zr, zi);                      // over high digit (regs)
    float k1f = (float)k1l;
#define TWL(r) { float aa = k1f * ((float)(r) * (1.0f/256.0f)); \
                 float tc = cosr(aa), ts = SG*sinr(aa); \
                 float a_ = zr[(r)], b_ = zi[(r)]; \
                 zr[(r)] = tc*a_ - ts*b_; zi[(r)] = tc*b_ + ts*a_; }
    REP15(TWL)
#undef TWL
#define TST(r) tb[16*(r) + (k1l ^ (r))] = make_float2(zr[(r)], zi[(r)]);
    REP16(TST)
#undef TST
    wsync();
#define TLD(c) { float2 v_ = tb[16*k1l + ((c) ^ k1l)]; zr[(c)]=v_.x; zi[(c)]=v_.y; }
    REP16(TLD)
#undef TLD
    wsync();
    fft16v<SIGN>(zr, zi);                      // over low digit (now regs)
}

// ============================================================
__global__ __launch_bounds__(256) void k_init(const float* __restrict__ win,
                                              float* __restrict__ wsqi){
    int i = blockIdx.x*256 + threadIdx.x;
    if (i < XPLEN){
        int n = i;
        int tmax = n / HOP; if (tmax > TFRAMES-1) tmax = TFRAMES-1;
        int tmin = (n - 511 + (HOP-1)) / HOP; if (tmin < 0) tmin = 0;
        float acc = 0.f;
        for (int t = tmin; t <= tmax; ++t){ float w = win[n - t*HOP]; acc += w*w; }
        wsqi[i] = 1.0f / (acc > 1e-11f ? acc : 1.0f);
    }
}

// slot-reconstructed signal reads
__device__ __forceinline__ float xs(const float* __restrict__ Sb,
                                    const float* __restrict__ wsq, int p){
    int bxp = p / BSTRIDE, r = p - bxp*BSTRIDE;
    float a = 0.f;
    if (bxp < NBLK) a = Sb[(size_t)bxp*SLOT + r];
    if (r < HALO && bxp > 0) a += Sb[(size_t)(bxp-1)*SLOT + BSTRIDE + r];
    return a * wsq[p];
}
__device__ __forceinline__ float2 xs2(const float* __restrict__ Sb,
                                      const float* __restrict__ wsq, int p){ // p even
    int bxp = p / BSTRIDE, r = p - bxp*BSTRIDE;
    float2 acc = make_float2(0.f, 0.f);
    if (bxp < NBLK) acc = *(const float2*)(Sb + (size_t)bxp*SLOT + r);
    if (r < HALO && bxp > 0){
        float2 h = *(const float2*)(Sb + (size_t)(bxp-1)*SLOT + BSTRIDE + r);
        acc.x += h.x; acc.y += h.y;
    }
    float2 q = *(const float2*)(wsq + p);
    return make_float2(acc.x*q.x, acc.y*q.y);
}

// window + scale -> per-frame LDS buffer; then block OLA -> slot
__device__ __forceinline__ void tail_store(const f16v& zr, const f16v& zi,
                                           const float2* WL, float2* tb,
                                           const float2* XB,
                                           float* __restrict__ Sw,
                                           int b, int bx, int tid, int k1l){
    constexpr float SC = 1.f/256.f;
#define TSR(c) { int m_ = k1l + 16*(c); float2 wv_ = WL[m_]; \
                 tb[m_] = make_float2(zr[(c)]*wv_.x*SC, zi[(c)]*wv_.y*SC); }
    REP16(TSR)
#undef TSR
    __syncthreads();
    float2* slot2 = (float2*)(Sw + ((size_t)b*NBLK + bx)*SLOT);
#pragma unroll
    for (int j=0;j<7;++j){
        int u = tid + 128*j;
        if (u < SPAN/2){
            float2 acc = make_float2(0.f, 0.f);
            int f1 = u/80;            if (f1 > 7) f1 = 7;
            int f0 = (u - 176)/80;    if (f0 < 0) f0 = 0;   // ceil((u-255)/80)
            for (int f = f0; f <= f1; ++f){
                float2 v = XB[f*GSTRIDE + (u - 80*f)];
                acc.x += v.x; acc.y += v.y;
            }
            slot2[u] = acc;
        }
    }
}

// ============================================================
// k_gl: one Griffin-Lim iteration. 128 thr = 2 waves; each 16-lane
// group owns one frame -> 4 frames per wave concurrently in flight.
// ============================================================
__global__ __launch_bounds__(128,3) void k_gl(const float* __restrict__ Sr,
                                              float* __restrict__ Sw,
                                              const float* __restrict__ mag,
                                              const float* __restrict__ win,
                                              const float* __restrict__ wsq){
    __shared__ __align__(16) float2 XB[8*GSTRIDE];   // transpose bufs, reused as frame bufs
    __shared__ __align__(16) float2 WL[256];         // window pairs
    int tid = threadIdx.x, w = tid>>6, lane = tid&63;
    int g = lane>>4, k1l = lane&15;
    int b = blockIdx.y, bx = blockIdx.x;

    WL[tid]     = ((const float2*)win)[tid];
    WL[tid+128] = ((const float2*)win)[tid+128];
    __syncthreads();

    int fidx = 4*w + g;
    int t = bx*8 + fidx;
    float2* tb = XB + fidx*GSTRIDE;
    const float* Sb   = Sr  + (size_t)b*SB;
    const float* magp = mag + ((size_t)b*TFRAMES + (size_t)t)*NBINS;

    // ---- load frame (packed even/odd, windowed): z[n], n = 16*reg + k1l
    f16v zr, zi;
    bool edge = (t < 2) | (t >= TFRAMES-2);
    if (!edge){
        int pb = t*HOP;
#define LDQ(r) { int m_ = 16*(r) + k1l; \
                 float2 v_ = xs2(Sb, wsq, pb + 2*m_); \
                 float2 wv_ = WL[m_]; \
                 zr[(r)] = v_.x*wv_.x; zi[(r)] = v_.y*wv_.y; }
        REP16(LDQ)
#undef LDQ
    } else {
#define LDE(r) { int m_ = 16*(r) + k1l; \
                 int p0_ = t*HOP + 2*m_, p1_ = p0_+1; \
                 int n0_ = (p0_<256)?(512-p0_):((p0_>=LOUT+256)?(2*LOUT+510-p0_):p0_); \
                 int n1_ = (p1_<256)?(512-p1_):((p1_>=LOUT+256)?(2*LOUT+510-p1_):p1_); \
                 float2 wv_ = WL[m_]; \
                 zr[(r)] = xs(Sb, wsq, n0_)*wv_.x; \
                 zi[(r)] = xs(Sb, wsq, n1_)*wv_.y; }
        REP16(LDE)
#undef LDE
    }

    // ---- forward FFT: Z[k] at (lane=k&15, reg=k>>4)
    fft256v<-1>(zr, zi, tb, k1l);

    // ---- mirror Y[c] = Z[(256-k)&255], k = k1l + 16c  (intra-group bpermute)
    int pl = (lane & 48) | ((16 - k1l) & 15);
    int am = pl << 2;
    bool l0 = (k1l == 0);
    f16v yr, yi;
#define MIR(c) { float gr_ = bperm(am, zr[15-(c)]); \
                 float gi_ = bperm(am, zi[15-(c)]); \
                 yr[(c)] = l0 ? zr[(16-(c))&15] : gr_; \
                 yi[(c)] = l0 ? zi[(16-(c))&15] : gi_; }
    REP16(MIR)
#undef MIR

    // ---- spectral projection (r6-verbatim math), in-place into z
    float a0 = (float)k1l * (1.0f/512.0f);
#define SPC(c) { float aa = a0 + (float)(c)*(1.0f/32.0f); \
        float tc = cosr(aa), ts = sinr(aa); \
        float zrr = zr[(c)], zii = zi[(c)]; \
        float Xer = 0.5f*(zrr+yr[(c)]), Xei = 0.5f*(zii-yi[(c)]); \
        float Dr = zrr-yr[(c)], Di = zii+yi[(c)]; \
        float Xor = 0.5f*Di, Xoi = -0.5f*Dr; \
        float Or = tc*Xor + ts*Xoi; \
        float Oi = tc*Xoi - ts*Xor; \
        float X1r = Xer + Or, X1i = Xei + Oi; \
        float X2r = Xer - Or, X2i = Oi - Xei; \
        float q1 = X1r*X1r + X1i*X1i; \
        bool ok1 = q1 > 1e-30f; \
        float v1 = ok1 ? __builtin_amdgcn_rsqf(q1) : 0.f; \
        float c1 = ok1 ? X1r*v1 : 1.f, s1 = X1i*v1; \
        float q2 = X2r*X2r + X2i*X2i; \
        bool ok2 = q2 > 1e-30f; \
        float v2 = ok2 ? __builtin_amdgcn_rsqf(q2) : 0.f; \
        float c2 = ok2 ? X2r*v2 : 1.f, s2 = X2i*v2; \
        int k_ = k1l + 16*(c); \
        float m1 = magp[k_], m2 = magp[256-k_]; \
        float S1r = m1*c1, S1i = m1*s1; \
        float S2r = m2*c2, S2i = m2*s2; \
        float Aer = 0.5f*(S1r+S2r), Aei = 0.5f*(S1i-S2i); \
        float Er = S1r - S2r, Ei = S1i + S2i; \
        float Bor = 0.5f*(tc*Er - ts*Ei); \
        float Boi = 0.5f*(tc*Ei + ts*Er); \
        zr[(c)] = Aer - Boi; \
        zi[(c)] = Aei + Bor; }
    REP16(SPC)
#undef SPC

    // ---- inverse FFT: time pairs at m = k1l + 16*reg
    fft256v<+1>(zr, zi, tb, k1l);

    tail_store(zr, zi, WL, tb, XB, Sw, b, bx, tid, k1l);
}

// ============================================================
// k_inv0s: iteration-0 istft from (mag, angles_init) -> slots
// ============================================================
__global__ __launch_bounds__(128,3) void k_inv0s(const float* __restrict__ mag,
                                                 const float* __restrict__ ang,
                                                 const float* __restrict__ win,
                                                 float* __restrict__ Sw){
    __shared__ __align__(16) float2 XB[8*GSTRIDE];
    __shared__ __align__(16) float2 WL[256];
    int tid = threadIdx.x, w = tid>>6, lane = tid&63;
    int g = lane>>4, k1l = lane&15;
    int b = blockIdx.y, bx = blockIdx.x;

    WL[tid]     = ((const float2*)win)[tid];
    WL[tid+128] = ((const float2*)win)[tid+128];
    __syncthreads();

    int fidx = 4*w + g;
    int t = bx*8 + fidx;
    float2* tb = XB + fidx*GSTRIDE;
    const float* magp = mag + ((size_t)b*TFRAMES + (size_t)t)*NBINS;
    const float* angp = ang + ((size_t)b*TFRAMES + (size_t)t)*NBINS;

    int pl = (lane & 48) | ((16 - k1l) & 15);
    int am = pl << 2;
    bool l0 = (k1l == 0);

    // ---- S[k] at (lane=k&15, reg=k>>4); Im(S[0]) zeroed (irfft semantics)
    f16v zr, zi;
#define LD0(r) { int k_ = 16*(r) + k1l; \
                 float m_ = magp[k_], an_ = angp[k_]; \
                 float sn_, cs_; sincosf(an_, &sn_, &cs_); \
                 zr[(r)] = m_*cs_; \
                 zi[(r)] = ((r)==0 && l0) ? 0.f : m_*sn_; }
    REP16(LD0)
#undef LD0
    float nyr = magp[256]*cosf(angp[256]);    // Nyquist (imag zeroed)

    // ---- mirror S[256-k]
    f16v yr, yi;
#define MIRN(c) { float gr_ = bperm(am, zr[15-(c)]); \
                  float gi_ = bperm(am, zi[15-(c)]); \
                  float lr_ = ((c)==0) ? nyr : zr[(16-(c))&15]; \
                  float li_ = ((c)==0) ? 0.f : zi[(16-(c))&15]; \
                  yr[(c)] = l0 ? lr_ : gr_; \
                  yi[(c)] = l0 ? li_ : gi_; }
    REP16(MIRN)
#undef MIRN

    // ---- c2r pack -> P
    float a0 = (float)k1l * (1.0f/512.0f);
#define C2R(c) { float aa = a0 + (float)(c)*(1.0f/32.0f); \
        float tc = cosr(aa), ts = sinr(aa); \
        float sr = zr[(c)], si = zi[(c)]; \
        float Aer = 0.5f*(sr + yr[(c)]), Aei = 0.5f*(si - yi[(c)]); \
        float Er = sr - yr[(c)], Ei = si + yi[(c)]; \
        float Bor = 0.5f*(tc*Er - ts*Ei); \
        float Boi = 0.5f*(tc*Ei + ts*Er); \
        zr[(c)] = Aer - Boi; \
        zi[(c)] = Aei + Bor; }
    REP16(C2R)
#undef C2R

    fft256v<+1>(zr, zi, tb, k1l);

    tail_store(zr, zi, WL, tb, XB, Sw, b, bx, tid, k1l);
}

// ============================================================
__global__ __launch_bounds__(128) void k_out(const float* __restrict__ S,
                                             const float* __restrict__ wsq,
                                             float* __restrict__ out){
    int b = blockIdx.y;
    int idx = blockIdx.x*128 + threadIdx.x;
    if (idx >= LOUT/2) return;
    const float* Sb = S + (size_t)b*SB;
    float2 v = xs2(Sb, wsq, 256 + 2*idx);
    ((float2*)(out + (size_t)b*LOUT))[idx] = v;
}

// ============================================================
extern "C" void kernel_launch(void* const* d_in, const int* in_sizes, int n_in,
                              void* d_out, int out_size, void* d_ws, size_t ws_size,
                              hipStream_t stream) {
    const float* mag  = (const float*)d_in[0];
    const float* ang0 = (const float*)d_in[1];
    const float* win  = (const float*)d_in[2];
    float* ws = (float*)d_ws;
    float* S[2] = { ws, ws + SBUF };
    float* wsqi = ws + 2*SBUF;
    float* outp = (float*)d_out;

    k_init<<<(XPLEN + 255)/256, 256, 0, stream>>>(win, wsqi);

    dim3 g(NBLK, BATCH);
    k_inv0s<<<g, 128, 0, stream>>>(mag, ang0, win, S[0]);
    for (int it = 0; it < NITER; ++it){
        k_gl<<<g, 128, 0, stream>>>(S[it%2], S[(it+1)%2], mag, win, wsqi);
    }
    k_out<<<dim3(640, BATCH), 128, 0, stream>>>(S[NITER%2], wsqi, outp);
}

// Round 6
// 1477.345 us; speedup vs baseline: 2.3209x; 2.3209x over previous
//
#include <hip/hip_runtime.h>
#include <math.h>

#define BATCH 32
#define TFRAMES 1024
#define NBINS 257
#define NFFT 512
#define HOP 160
#define LOUT 163680
#define XPLEN 164192
#define NITER 32
#define FPW 4                        // frames per wave
#define WSTRIDE (FPW*HOP)            // 640
#define BSTRIDE (2*WSTRIDE)          // 1280 (block = 2 waves = 8 frames)
#define HALO (NFFT-HOP)              // 352
#define WSPAN (WSTRIDE+HALO)         // 992  per-wave OLA span
#define SPAN (BSTRIDE+HALO)          // 1632 per-block OLA span
#define NBLK 128                     // blocks per batch row
#define SLOT SPAN
#define SB ((size_t)NBLK*SLOT)
#define SBUF ((size_t)BATCH*SB)

#define P2(i) ((i) + ((i) >> 4))     // float2-index pad: breaks 16-way aliasing

__device__ __forceinline__ float cosr(float x){ return __builtin_amdgcn_cosf(x); }
__device__ __forceinline__ float sinr(float x){ return __builtin_amdgcn_sinf(x); }
__device__ __forceinline__ void wsync(){
    __builtin_amdgcn_fence(__ATOMIC_SEQ_CST, "wavefront");
    __builtin_amdgcn_wave_barrier();
}
__device__ __forceinline__ float bperm(int addr, float v){
    return __int_as_float(__builtin_amdgcn_ds_bpermute(addr, __float_as_int(v)));
}

struct Tw { float c1,s1,c2,s2,c3,s3; };
__device__ __forceinline__ Tw twset(float x){
    Tw t; float c=cosr(x), s=sinr(x);
    t.c1=c; t.s1=s;
    t.c2=c*c-s*s; t.s2=2.f*c*s;
    t.c3=t.c2*c-t.s2*s; t.s3=t.c2*s+t.s2*c;
    return t;
}

template<int SIGN, bool TWID>
__device__ __forceinline__ void bfly4(const float xr[4], const float xi[4],
                                      const Tw& t, float yr[4], float yi[4]){
    constexpr float SG = (SIGN>0)?1.f:-1.f;
    float apc_r=xr[0]+xr[2], apc_i=xi[0]+xi[2];
    float amc_r=xr[0]-xr[2], amc_i=xi[0]-xi[2];
    float bpd_r=xr[1]+xr[3], bpd_i=xi[1]+xi[3];
    float bmd_r=xr[1]-xr[3], bmd_i=xi[1]-xi[3];
    yr[0]=apc_r+bpd_r; yi[0]=apc_i+bpd_i;
    float u2r=apc_r-bpd_r, u2i=apc_i-bpd_i;
    float u1r=amc_r-SG*bmd_i, u1i=amc_i+SG*bmd_r;
    float u3r=amc_r+SG*bmd_i, u3i=amc_i-SG*bmd_r;
    if (TWID){
        float s1=SG*t.s1, s2=SG*t.s2, s3=SG*t.s3;
        yr[1]=t.c1*u1r-s1*u1i; yi[1]=t.c1*u1i+s1*u1r;
        yr[2]=t.c2*u2r-s2*u2i; yi[2]=t.c2*u2i+s2*u2r;
        yr[3]=t.c3*u3r-s3*u3i; yi[3]=t.c3*u3i+s3*u3r;
    } else {
        yr[1]=u1r; yi[1]=u1i; yr[2]=u2r; yi[2]=u2i; yr[3]=u3r; yi[3]=u3i;
    }
}

// 256-pt complex FFT per wave, radix-4 Stockham, regs in/out.
// ONE float2 LDS buffer: b64 exchanges (half the DS ops of split re/im).
template<int SIGN>
__device__ __forceinline__ void fft256reg(float xr[4], float xi[4],
                                          float2* __restrict__ bz,
                                          const Tw& tw0, const Tw& tw1, const Tw& tw2,
                                          int lane){
    float yr[4], yi[4], ar[4], ai[4];
    bfly4<SIGN,true>(xr, xi, tw0, yr, yi);
    { int o = 4*lane;
#pragma unroll
      for (int c=0;c<4;++c) bz[P2(o+c)] = make_float2(yr[c], yi[c]); }
    wsync();
#pragma unroll
    for (int c=0;c<4;++c){ float2 v = bz[P2(lane+64*c)]; ar[c]=v.x; ai[c]=v.y; }
    wsync();
    bfly4<SIGN,true>(ar, ai, tw1, yr, yi);
    { int o = (lane&3) + 16*(lane>>2);
#pragma unroll
      for (int c=0;c<4;++c) bz[P2(o+4*c)] = make_float2(yr[c], yi[c]); }
    wsync();
#pragma unroll
    for (int c=0;c<4;++c){ float2 v = bz[P2(lane+64*c)]; ar[c]=v.x; ai[c]=v.y; }
    wsync();
    bfly4<SIGN,true>(ar, ai, tw2, yr, yi);
    { int o = (lane&15) + 64*(lane>>4);
#pragma unroll
      for (int c=0;c<4;++c) bz[P2(o+16*c)] = make_float2(yr[c], yi[c]); }
    wsync();
#pragma unroll
    for (int c=0;c<4;++c){ float2 v = bz[P2(lane+64*c)]; ar[c]=v.x; ai[c]=v.y; }
    wsync();
    bfly4<SIGN,false>(ar, ai, tw0, xr, xi);
}

// ============================================================
__global__ __launch_bounds__(256) void k_init(const float* __restrict__ win,
                                              float* __restrict__ wsqi){
    int i = blockIdx.x*256 + threadIdx.x;
    if (i < XPLEN){
        int n = i;
        int tmax = n / HOP; if (tmax > TFRAMES-1) tmax = TFRAMES-1;
        int tmin = (n - (NFFT-1) + (HOP-1)) / HOP; if (tmin < 0) tmin = 0;
        float acc = 0.f;
        for (int t = tmin; t <= tmax; ++t){ float w = win[n - t*HOP]; acc += w*w; }
        wsqi[i] = 1.0f / (acc > 1e-11f ? acc : 1.0f);
    }
}

// slot-reconstructed signal reads
__device__ __forceinline__ float xs(const float* __restrict__ Sb,
                                    const float* __restrict__ wsq, int p){
    int bxp = p / BSTRIDE, r = p - bxp*BSTRIDE;
    float a = 0.f;
    if (bxp < NBLK) a = Sb[(size_t)bxp*SLOT + r];
    if (r < HALO && bxp > 0) a += Sb[(size_t)(bxp-1)*SLOT + BSTRIDE + r];
    return a * wsq[p];
}
__device__ __forceinline__ float2 xs2(const float* __restrict__ Sb,
                                      const float* __restrict__ wsq, int p){ // p even
    int bxp = p / BSTRIDE, r = p - bxp*BSTRIDE;
    float2 acc = make_float2(0.f, 0.f);
    if (bxp < NBLK) acc = *(const float2*)(Sb + (size_t)bxp*SLOT + r);
    if (r < HALO && bxp > 0){
        float2 h = *(const float2*)(Sb + (size_t)(bxp-1)*SLOT + BSTRIDE + r);
        acc.x += h.x; acc.y += h.y;
    }
    float2 q = *(const float2*)(wsq + p);
    return make_float2(acc.x*q.x, acc.y*q.y);
}

// inverse tail: pack regs -> inv FFT -> window -> private per-wave sacc
__device__ __forceinline__ void inv_accum(float pr[4], float pi[4],
                                          float2* __restrict__ bz,
                                          const Tw& tw0, const Tw& tw1, const Tw& tw2,
                                          const float wA[4], const float wB[4],
                                          int lane, int f, float2* sa2){
    fft256reg<+1>(pr, pi, bz, tw0, tw1, tw2, lane);
    constexpr float SC = 1.f/256.f;
    int base2 = f*(HOP/2);
#pragma unroll
    for (int c=0;c<4;++c){
        int u = base2 + lane + 64*c;
        float2 v = sa2[u];
        v.x += pr[c]*wA[c]*SC;
        v.y += pi[c]*wB[c]*SC;
        sa2[u] = v;
    }
    wsync();
}

__device__ __forceinline__ void slot_store(float* __restrict__ Sw, int b, int bx,
                                           const float* s0, const float* s1, int tid){
    float2* slot2 = (float2*)(Sw + ((size_t)b*NBLK + bx)*SLOT);
    const float2* s0_2 = (const float2*)s0;
    const float2* s1_2 = (const float2*)s1;
#pragma unroll
    for (int j=0;j<7;++j){
        int u = tid + 128*j;
        if (u < SPAN/2){
            float2 v = make_float2(0.f, 0.f);
            if (u < WSPAN/2) v = s0_2[u];
            if (u >= WSTRIDE/2){
                float2 w1 = s1_2[u - WSTRIDE/2];
                v.x += w1.x; v.y += w1.y;
            }
            slot2[u] = v;
        }
    }
}

// frame load (r6-verbatim logic)
__device__ __forceinline__ void load_frame(const float* __restrict__ Sb,
                                           const float* __restrict__ wsq,
                                           int t, int lane,
                                           const float wA[4], const float wB[4],
                                           float fr[4], float fi[4]){
    bool edge = (t < 2) | (t >= TFRAMES-2);
    if (!edge){
        int pb = t*HOP;
#pragma unroll
        for (int c=0;c<4;++c){
            int p = pb + 2*(lane + 64*c);
            float2 v = xs2(Sb, wsq, p);
            fr[c] = v.x*wA[c];
            fi[c] = v.y*wB[c];
        }
    } else {
#pragma unroll
        for (int c=0;c<4;++c){
            int m = lane + 64*c;
            int p0 = t*HOP + 2*m, p1 = p0+1;
            int n0 = (p0<256)?(512-p0):((p0>=LOUT+256)?(2*LOUT+510-p0):p0);
            int n1 = (p1<256)?(512-p1):((p1>=LOUT+256)?(2*LOUT+510-p1):p1);
            fr[c] = xs(Sb, wsq, n0)*wA[c];
            fi[c] = xs(Sb, wsq, n1)*wB[c];
        }
    }
}

// mag prefetch for one frame: m1[c]=mag[k], m2[c]=mag[256-k], k=lane+64c
__device__ __forceinline__ void load_mag(const float* __restrict__ magp, int lane,
                                         float m1[4], float m2[4]){
#pragma unroll
    for (int c=0;c<4;++c){
        int k = lane + 64*c;
        m1[c] = magp[k];
        m2[c] = magp[256-k];
    }
}

// spectral projection (r6-verbatim math; mag values pre-loaded)
__device__ __forceinline__ void spectral(const float fr[4], const float fi[4],
                                         const float yr[4], const float yi[4],
                                         const float m1a[4], const float m2a[4],
                                         const float twc[4], const float tws[4],
                                         float pr[4], float pi[4]){
#pragma unroll
    for (int c=0;c<4;++c){
        float zr = fr[c], zi = fi[c];
        float Xer = 0.5f*(zr+yr[c]), Xei = 0.5f*(zi-yi[c]);
        float Dr = zr-yr[c], Di = zi+yi[c];
        float Xor = 0.5f*Di, Xoi = -0.5f*Dr;
        float Or = twc[c]*Xor + tws[c]*Xoi;
        float Oi = twc[c]*Xoi - tws[c]*Xor;
        float X1r = Xer + Or, X1i = Xei + Oi;
        float X2r = Xer - Or, X2i = Oi - Xei;
        float q1 = X1r*X1r + X1i*X1i;
        bool ok1 = q1 > 1e-30f;
        float v1 = ok1 ? __builtin_amdgcn_rsqf(q1) : 0.f;
        float c1 = ok1 ? X1r*v1 : 1.f, s1 = X1i*v1;
        float q2 = X2r*X2r + X2i*X2i;
        bool ok2 = q2 > 1e-30f;
        float v2 = ok2 ? __builtin_amdgcn_rsqf(q2) : 0.f;
        float c2 = ok2 ? X2r*v2 : 1.f, s2 = X2i*v2;
        float m1 = m1a[c], m2 = m2a[c];
        float S1r = m1*c1, S1i = m1*s1;
        float S2r = m2*c2, S2i = m2*s2;
        float Aer = 0.5f*(S1r+S2r), Aei = 0.5f*(S1i-S2i);
        float Er = S1r - S2r, Ei = S1i + S2i;
        float Bor = 0.5f*(twc[c]*Er - tws[c]*Ei);
        float Boi = 0.5f*(twc[c]*Ei + tws[c]*Er);
        pr[c] = Aer - Boi;
        pi[c] = Aei + Bor;
    }
}

// ============================================================
// k_gl: one Griffin-Lim iteration. block = 2 waves x 4 frames.
// b64 FFT exchanges; mirror via ds_bpermute (reg swap + lane 64-l).
// T14 pipeline: frame f+1's global loads (samples + mag) issue before
// frame f's FFT -- bit-identical values, latency hidden under compute.
// ============================================================
__global__ __launch_bounds__(128,4) void k_gl(const float* __restrict__ Sr,
                                              float* __restrict__ Sw,
                                              const float* __restrict__ mag,
                                              const float* __restrict__ win,
                                              const float* __restrict__ wsq){
    __shared__ __align__(16) float sacc[2][WSPAN];
    __shared__ __align__(16) float2 BZ[2][274];
    int tid = threadIdx.x, w = tid>>6, lane = tid&63;
    int b = blockIdx.y, bx = blockIdx.x;

    float2* bz = BZ[w];
    float2* sa2 = (float2*)sacc[w];

    Tw tw0 = twset((float)lane * (1.f/256.f));
    Tw tw1 = twset((float)(lane>>2) * (1.f/64.f));
    Tw tw2 = twset((float)(lane>>4) * (1.f/16.f));
    float twc[4], tws[4], wA[4], wB[4];
#pragma unroll
    for (int c=0;c<4;++c){
        int k = lane + 64*c;
        float x = (float)k * (1.f/512.f);
        twc[c]=cosr(x); tws[c]=sinr(x);
        float2 wv = ((const float2*)win)[k];
        wA[c]=wv.x; wB[c]=wv.y;
    }
    int am = ((64 - lane) & 63) << 2;    // mirror partner lane address
    bool l0 = (lane == 0);
#pragma unroll
    for (int j=0;j<8;++j){ int u = lane + 64*j; if (u < WSPAN/2) sa2[u]=make_float2(0.f,0.f); }
    __syncthreads();

    const float* Sb = Sr + (size_t)b*SB;
    const float* magb = mag + ((size_t)b*TFRAMES)*NBINS;
    int t0 = (bx*2 + w)*FPW;

    // ---- pipeline prologue: frame 0 loads
    float fr[4], fi[4], pm1[4], pm2[4];
    load_frame(Sb, wsq, t0, lane, wA, wB, fr, fi);
    load_mag(magb + (size_t)t0*NBINS, lane, pm1, pm2);

#pragma unroll 1
    for (int f=0; f<FPW; ++f){
        int t = t0 + f;

        // ---- issue next frame's loads (independent of everything below)
        float nfr[4], nfi[4], nm1[4], nm2[4];
        if (f+1 < FPW){
            load_frame(Sb, wsq, t+1, lane, wA, wB, nfr, nfi);
            load_mag(magb + (size_t)(t+1)*NBINS, lane, nm1, nm2);
        }

        // forward FFT of packed frame (regs, natural order out)
        fft256reg<-1>(fr, fi, bz, tw0, tw1, tw2, lane);

        // mirror via bpermute: y[c] = Z[(256-(lane+64c))&255]
        float yr[4], yi[4];
#pragma unroll
        for (int c=0;c<4;++c){
            float gr = bperm(am, fr[3-c]);
            float gi = bperm(am, fi[3-c]);
            yr[c] = l0 ? fr[(4-c)&3] : gr;
            yi[c] = l0 ? fi[(4-c)&3] : gi;
        }

        float pr[4], pi[4];
        spectral(fr, fi, yr, yi, pm1, pm2, twc, tws, pr, pi);

        inv_accum(pr, pi, bz, tw0, tw1, tw2, wA, wB, lane, f, sa2);

        // ---- rotate pipeline registers
        if (f+1 < FPW){
#pragma unroll
            for (int c=0;c<4;++c){
                fr[c]=nfr[c]; fi[c]=nfi[c];
                pm1[c]=nm1[c]; pm2[c]=nm2[c];
            }
        }
    }
    __syncthreads();
    slot_store(Sw, b, bx, sacc[0], sacc[1], tid);
}

// ============================================================
// k_inv0s: iteration-0 istft from (mag, angles_init) -> slots
// ============================================================
__global__ __launch_bounds__(128,4) void k_inv0s(const float* __restrict__ mag,
                                                 const float* __restrict__ ang,
                                                 const float* __restrict__ win,
                                                 float* __restrict__ Sw){
    __shared__ __align__(16) float sacc[2][WSPAN];
    __shared__ __align__(16) float2 BZ[2][274];
    int tid = threadIdx.x, w = tid>>6, lane = tid&63;
    int b = blockIdx.y, bx = blockIdx.x;

    float2* bz = BZ[w];
    float2* sa2 = (float2*)sacc[w];

    Tw tw0 = twset((float)lane * (1.f/256.f));
    Tw tw1 = twset((float)(lane>>2) * (1.f/64.f));
    Tw tw2 = twset((float)(lane>>4) * (1.f/16.f));
    float twc[4], tws[4], wA[4], wB[4];
#pragma unroll
    for (int c=0;c<4;++c){
        int k = lane + 64*c;
        float x = (float)k * (1.f/512.f);
        twc[c]=cosr(x); tws[c]=sinr(x);
        float2 wv = ((const float2*)win)[k];
        wA[c]=wv.x; wB[c]=wv.y;
    }
#pragma unroll
    for (int j=0;j<8;++j){ int u = lane + 64*j; if (u < WSPAN/2) sa2[u]=make_float2(0.f,0.f); }
    __syncthreads();

    const float* magb = mag + ((size_t)b*TFRAMES)*NBINS;
    const float* angb = ang + ((size_t)b*TFRAMES)*NBINS;
    int t0 = (bx*2 + w)*FPW;

#pragma unroll 1
    for (int f=0; f<FPW; ++f){
        int t = t0 + f;
        const float* magp = magb + (size_t)t*NBINS;
        const float* angp = angb + (size_t)t*NBINS;
        float sr_[4], si_[4];
#pragma unroll
        for (int c=0;c<4;++c){
            int k = lane + 64*c;
            float m = magp[k], a = angp[k];
            float sn, cs;
            sincosf(a, &sn, &cs);
            sr_[c] = m*cs;
            si_[c] = (c==0 && lane==0) ? 0.f : m*sn;
        }
        // stage S (+Nyquist) for the c2r pack mirror (b64)
#pragma unroll
        for (int c=0;c<4;++c){ int k=lane+64*c; bz[P2(k)] = make_float2(sr_[c], si_[c]); }
        if (lane==0){
            bz[P2(256)] = make_float2(magp[256]*cosf(angp[256]), 0.f);
        }
        wsync();
        float pr[4], pi[4];
#pragma unroll
        for (int c=0;c<4;++c){
            int k = lane + 64*c;
            float2 yv = bz[P2(256-k)];
            float Aer = 0.5f*(sr_[c]+yv.x), Aei = 0.5f*(si_[c]-yv.y);
            float Er = sr_[c]-yv.x, Ei = si_[c]+yv.y;
            float Bor = 0.5f*(twc[c]*Er - tws[c]*Ei);
            float Boi = 0.5f*(twc[c]*Ei + tws[c]*Er);
            pr[c] = Aer - Boi;
            pi[c] = Aei + Bor;
        }
        wsync();
        inv_accum(pr, pi, bz, tw0, tw1, tw2, wA, wB, lane, f, sa2);
    }
    __syncthreads();
    slot_store(Sw, b, bx, sacc[0], sacc[1], tid);
}

// ============================================================
__global__ __launch_bounds__(128) void k_out(const float* __restrict__ S,
                                             const float* __restrict__ wsq,
                                             float* __restrict__ out){
    int b = blockIdx.y;
    int idx = blockIdx.x*128 + threadIdx.x;
    if (idx >= LOUT/2) return;
    const float* Sb = S + (size_t)b*SB;
    float2 v = xs2(Sb, wsq, 256 + 2*idx);
    ((float2*)(out + (size_t)b*LOUT))[idx] = v;
}

// ============================================================
extern "C" void kernel_launch(void* const* d_in, const int* in_sizes, int n_in,
                              void* d_out, int out_size, void* d_ws, size_t ws_size,
                              hipStream_t stream) {
    const float* mag  = (const float*)d_in[0];
    const float* ang0 = (const float*)d_in[1];
    const float* win  = (const float*)d_in[2];
    float* ws = (float*)d_ws;
    float* S[2] = { ws, ws + SBUF };
    float* wsqi = ws + 2*SBUF;
    float* outp = (float*)d_out;

    k_init<<<(XPLEN + 255)/256, 256, 0, stream>>>(win, wsqi);

    dim3 g(NBLK, BATCH);
    k_inv0s<<<g, 128, 0, stream>>>(mag, ang0, win, S[0]);
    for (int it = 0; it < NITER; ++it){
        k_gl<<<g, 128, 0, stream>>>(S[it%2], S[(it+1)%2], mag, win, wsqi);
    }
    k_out<<<dim3(640, BATCH), 128, 0, stream>>>(S[NITER%2], wsqi, outp);
}

// Round 7
// 1423.577 us; speedup vs baseline: 2.4085x; 1.0378x over previous
//
#include <hip/hip_runtime.h>
#include <math.h>

#define BATCH 32
#define TFRAMES 1024
#define NBINS 257
#define NFFT 512
#define HOP 160
#define LOUT 163680
#define XPLEN 164192
#define NITER 32
#define FPW 4                        // frames per wave
#define WSTRIDE (FPW*HOP)            // 640
#define BSTRIDE (2*WSTRIDE)          // 1280 (block = 2 waves = 8 frames)
#define HALO (NFFT-HOP)              // 352
#define WSPAN (WSTRIDE+HALO)         // 992  per-wave OLA span
#define SPAN (BSTRIDE+HALO)          // 1632 per-block OLA span
#define NBLK 128                     // blocks per batch row
#define SLOT SPAN
#define SB ((size_t)NBLK*SLOT)
#define SBUF ((size_t)BATCH*SB)

#define P2(i) ((i) + ((i) >> 4))     // float2-index pad: breaks 16-way aliasing

__device__ __forceinline__ float cosr(float x){ return __builtin_amdgcn_cosf(x); }
__device__ __forceinline__ float sinr(float x){ return __builtin_amdgcn_sinf(x); }
// BZ/sacc are wave-private: DS ops execute in program order within a wave,
// so no lgkmcnt(0) drain (fence) is needed between write and read rounds.
// wave_barrier = compiler scheduling fence only, emits no instructions.
__device__ __forceinline__ void wsync(){
    __builtin_amdgcn_wave_barrier();
}
__device__ __forceinline__ float bperm(int addr, float v){
    return __int_as_float(__builtin_amdgcn_ds_bpermute(addr, __float_as_int(v)));
}

struct Tw { float c1,s1,c2,s2,c3,s3; };
__device__ __forceinline__ Tw twset(float x){
    Tw t; float c=cosr(x), s=sinr(x);
    t.c1=c; t.s1=s;
    t.c2=c*c-s*s; t.s2=2.f*c*s;
    t.c3=t.c2*c-t.s2*s; t.s3=t.c2*s+t.s2*c;
    return t;
}

template<int SIGN, bool TWID>
__device__ __forceinline__ void bfly4(const float xr[4], const float xi[4],
                                      const Tw& t, float yr[4], float yi[4]){
    constexpr float SG = (SIGN>0)?1.f:-1.f;
    float apc_r=xr[0]+xr[2], apc_i=xi[0]+xi[2];
    float amc_r=xr[0]-xr[2], amc_i=xi[0]-xi[2];
    float bpd_r=xr[1]+xr[3], bpd_i=xi[1]+xi[3];
    float bmd_r=xr[1]-xr[3], bmd_i=xi[1]-xi[3];
    yr[0]=apc_r+bpd_r; yi[0]=apc_i+bpd_i;
    float u2r=apc_r-bpd_r, u2i=apc_i-bpd_i;
    float u1r=amc_r-SG*bmd_i, u1i=amc_i+SG*bmd_r;
    float u3r=amc_r+SG*bmd_i, u3i=amc_i-SG*bmd_r;
    if (TWID){
        float s1=SG*t.s1, s2=SG*t.s2, s3=SG*t.s3;
        yr[1]=t.c1*u1r-s1*u1i; yi[1]=t.c1*u1i+s1*u1r;
        yr[2]=t.c2*u2r-s2*u2i; yi[2]=t.c2*u2i+s2*u2r;
        yr[3]=t.c3*u3r-s3*u3i; yi[3]=t.c3*u3i+s3*u3r;
    } else {
        yr[1]=u1r; yi[1]=u1i; yr[2]=u2r; yi[2]=u2i; yr[3]=u3r; yi[3]=u3i;
    }
}

// 256-pt complex FFT per wave, radix-4 Stockham, regs in/out.
// ONE float2 LDS buffer: b64 exchanges (half the DS ops of split re/im).
template<int SIGN>
__device__ __forceinline__ void fft256reg(float xr[4], float xi[4],
                                          float2* __restrict__ bz,
                                          const Tw& tw0, const Tw& tw1, const Tw& tw2,
                                          int lane){
    float yr[4], yi[4], ar[4], ai[4];
    bfly4<SIGN,true>(xr, xi, tw0, yr, yi);
    { int o = 4*lane;
#pragma unroll
      for (int c=0;c<4;++c) bz[P2(o+c)] = make_float2(yr[c], yi[c]); }
    wsync();
#pragma unroll
    for (int c=0;c<4;++c){ float2 v = bz[P2(lane+64*c)]; ar[c]=v.x; ai[c]=v.y; }
    wsync();
    bfly4<SIGN,true>(ar, ai, tw1, yr, yi);
    { int o = (lane&3) + 16*(lane>>2);
#pragma unroll
      for (int c=0;c<4;++c) bz[P2(o+4*c)] = make_float2(yr[c], yi[c]); }
    wsync();
#pragma unroll
    for (int c=0;c<4;++c){ float2 v = bz[P2(lane+64*c)]; ar[c]=v.x; ai[c]=v.y; }
    wsync();
    bfly4<SIGN,true>(ar, ai, tw2, yr, yi);
    { int o = (lane&15) + 64*(lane>>4);
#pragma unroll
      for (int c=0;c<4;++c) bz[P2(o+16*c)] = make_float2(yr[c], yi[c]); }
    wsync();
#pragma unroll
    for (int c=0;c<4;++c){ float2 v = bz[P2(lane+64*c)]; ar[c]=v.x; ai[c]=v.y; }
    wsync();
    bfly4<SIGN,false>(ar, ai, tw0, xr, xi);
}

// ============================================================
__global__ __launch_bounds__(256) void k_init(const float* __restrict__ win,
                                              float* __restrict__ wsqi){
    int i = blockIdx.x*256 + threadIdx.x;
    if (i < XPLEN){
        int n = i;
        int tmax = n / HOP; if (tmax > TFRAMES-1) tmax = TFRAMES-1;
        int tmin = (n - (NFFT-1) + (HOP-1)) / HOP; if (tmin < 0) tmin = 0;
        float acc = 0.f;
        for (int t = tmin; t <= tmax; ++t){ float w = win[n - t*HOP]; acc += w*w; }
        wsqi[i] = 1.0f / (acc > 1e-11f ? acc : 1.0f);
    }
}

// slot-reconstructed signal reads
__device__ __forceinline__ float xs(const float* __restrict__ Sb,
                                    const float* __restrict__ wsq, int p){
    int bxp = p / BSTRIDE, r = p - bxp*BSTRIDE;
    float a = 0.f;
    if (bxp < NBLK) a = Sb[(size_t)bxp*SLOT + r];
    if (r < HALO && bxp > 0) a += Sb[(size_t)(bxp-1)*SLOT + BSTRIDE + r];
    return a * wsq[p];
}
__device__ __forceinline__ float2 xs2(const float* __restrict__ Sb,
                                      const float* __restrict__ wsq, int p){ // p even
    int bxp = p / BSTRIDE, r = p - bxp*BSTRIDE;
    float2 acc = make_float2(0.f, 0.f);
    if (bxp < NBLK) acc = *(const float2*)(Sb + (size_t)bxp*SLOT + r);
    if (r < HALO && bxp > 0){
        float2 h = *(const float2*)(Sb + (size_t)(bxp-1)*SLOT + BSTRIDE + r);
        acc.x += h.x; acc.y += h.y;
    }
    float2 q = *(const float2*)(wsq + p);
    return make_float2(acc.x*q.x, acc.y*q.y);
}

// inverse tail: pack regs -> inv FFT -> window -> private per-wave sacc
__device__ __forceinline__ void inv_accum(float pr[4], float pi[4],
                                          float2* __restrict__ bz,
                                          const Tw& tw0, const Tw& tw1, const Tw& tw2,
                                          const float wA[4], const float wB[4],
                                          int lane, int f, float2* sa2){
    fft256reg<+1>(pr, pi, bz, tw0, tw1, tw2, lane);
    constexpr float SC = 1.f/256.f;
    int base2 = f*(HOP/2);
#pragma unroll
    for (int c=0;c<4;++c){
        int u = base2 + lane + 64*c;
        float2 v = sa2[u];
        v.x += pr[c]*wA[c]*SC;
        v.y += pi[c]*wB[c]*SC;
        sa2[u] = v;
    }
    wsync();
}

__device__ __forceinline__ void slot_store(float* __restrict__ Sw, int b, int bx,
                                           const float* s0, const float* s1, int tid){
    float2* slot2 = (float2*)(Sw + ((size_t)b*NBLK + bx)*SLOT);
    const float2* s0_2 = (const float2*)s0;
    const float2* s1_2 = (const float2*)s1;
#pragma unroll
    for (int j=0;j<7;++j){
        int u = tid + 128*j;
        if (u < SPAN/2){
            float2 v = make_float2(0.f, 0.f);
            if (u < WSPAN/2) v = s0_2[u];
            if (u >= WSTRIDE/2){
                float2 w1 = s1_2[u - WSTRIDE/2];
                v.x += w1.x; v.y += w1.y;
            }
            slot2[u] = v;
        }
    }
}

// frame load (r6-verbatim logic)
__device__ __forceinline__ void load_frame(const float* __restrict__ Sb,
                                           const float* __restrict__ wsq,
                                           int t, int lane,
                                           const float wA[4], const float wB[4],
                                           float fr[4], float fi[4]){
    bool edge = (t < 2) | (t >= TFRAMES-2);
    if (!edge){
        int pb = t*HOP;
#pragma unroll
        for (int c=0;c<4;++c){
            int p = pb + 2*(lane + 64*c);
            float2 v = xs2(Sb, wsq, p);
            fr[c] = v.x*wA[c];
            fi[c] = v.y*wB[c];
        }
    } else {
#pragma unroll
        for (int c=0;c<4;++c){
            int m = lane + 64*c;
            int p0 = t*HOP + 2*m, p1 = p0+1;
            int n0 = (p0<256)?(512-p0):((p0>=LOUT+256)?(2*LOUT+510-p0):p0);
            int n1 = (p1<256)?(512-p1):((p1>=LOUT+256)?(2*LOUT+510-p1):p1);
            fr[c] = xs(Sb, wsq, n0)*wA[c];
            fi[c] = xs(Sb, wsq, n1)*wB[c];
        }
    }
}

// spectral projection (r6-verbatim math)
__device__ __forceinline__ void spectral(const float fr[4], const float fi[4],
                                         const float yr[4], const float yi[4],
                                         const float* __restrict__ magp,
                                         const float twc[4], const float tws[4],
                                         int lane, float pr[4], float pi[4]){
#pragma unroll
    for (int c=0;c<4;++c){
        int k = lane + 64*c;
        float zr = fr[c], zi = fi[c];
        float Xer = 0.5f*(zr+yr[c]), Xei = 0.5f*(zi-yi[c]);
        float Dr = zr-yr[c], Di = zi+yi[c];
        float Xor = 0.5f*Di, Xoi = -0.5f*Dr;
        float Or = twc[c]*Xor + tws[c]*Xoi;
        float Oi = twc[c]*Xoi - tws[c]*Xor;
        float X1r = Xer + Or, X1i = Xei + Oi;
        float X2r = Xer - Or, X2i = Oi - Xei;
        float q1 = X1r*X1r + X1i*X1i;
        bool ok1 = q1 > 1e-30f;
        float v1 = ok1 ? __builtin_amdgcn_rsqf(q1) : 0.f;
        float c1 = ok1 ? X1r*v1 : 1.f, s1 = X1i*v1;
        float q2 = X2r*X2r + X2i*X2i;
        bool ok2 = q2 > 1e-30f;
        float v2 = ok2 ? __builtin_amdgcn_rsqf(q2) : 0.f;
        float c2 = ok2 ? X2r*v2 : 1.f, s2 = X2i*v2;
        float m1 = magp[k], m2 = magp[256-k];
        float S1r = m1*c1, S1i = m1*s1;
        float S2r = m2*c2, S2i = m2*s2;
        float Aer = 0.5f*(S1r+S2r), Aei = 0.5f*(S1i-S2i);
        float Er = S1r - S2r, Ei = S1i + S2i;
        float Bor = 0.5f*(twc[c]*Er - tws[c]*Ei);
        float Boi = 0.5f*(twc[c]*Ei + tws[c]*Er);
        pr[c] = Aer - Boi;
        pi[c] = Aei + Bor;
    }
}

// ============================================================
// k_gl: one Griffin-Lim iteration. block = 2 waves x 4 frames.
// b64 FFT exchanges; mirror via ds_bpermute (reg swap + lane 64-l).
// ============================================================
__global__ __launch_bounds__(128,4) void k_gl(const float* __restrict__ Sr,
                                              float* __restrict__ Sw,
                                              const float* __restrict__ mag,
                                              const float* __restrict__ win,
                                              const float* __restrict__ wsq){
    __shared__ __align__(16) float sacc[2][WSPAN];
    __shared__ __align__(16) float2 BZ[2][274];
    int tid = threadIdx.x, w = tid>>6, lane = tid&63;
    int b = blockIdx.y, bx = blockIdx.x;

    float2* bz = BZ[w];
    float2* sa2 = (float2*)sacc[w];

    Tw tw0 = twset((float)lane * (1.f/256.f));
    Tw tw1 = twset((float)(lane>>2) * (1.f/64.f));
    Tw tw2 = twset((float)(lane>>4) * (1.f/16.f));
    float twc[4], tws[4], wA[4], wB[4];
#pragma unroll
    for (int c=0;c<4;++c){
        int k = lane + 64*c;
        float x = (float)k * (1.f/512.f);
        twc[c]=cosr(x); tws[c]=sinr(x);
        float2 wv = ((const float2*)win)[k];
        wA[c]=wv.x; wB[c]=wv.y;
    }
    int am = ((64 - lane) & 63) << 2;    // mirror partner lane address
    bool l0 = (lane == 0);
#pragma unroll
    for (int j=0;j<8;++j){ int u = lane + 64*j; if (u < WSPAN/2) sa2[u]=make_float2(0.f,0.f); }
    __syncthreads();

    const float* Sb = Sr + (size_t)b*SB;
    const float* magb = mag + ((size_t)b*TFRAMES)*NBINS;
    int t0 = (bx*2 + w)*FPW;

#pragma unroll 1
    for (int f=0; f<FPW; ++f){
        int t = t0 + f;
        float fr[4], fi[4];
        load_frame(Sb, wsq, t, lane, wA, wB, fr, fi);

        // forward FFT of packed frame (regs, natural order out)
        fft256reg<-1>(fr, fi, bz, tw0, tw1, tw2, lane);

        // mirror via bpermute: y[c] = Z[(256-(lane+64c))&255]
        float yr[4], yi[4];
#pragma unroll
        for (int c=0;c<4;++c){
            float gr = bperm(am, fr[3-c]);
            float gi = bperm(am, fi[3-c]);
            yr[c] = l0 ? fr[(4-c)&3] : gr;
            yi[c] = l0 ? fi[(4-c)&3] : gi;
        }

        float pr[4], pi[4];
        spectral(fr, fi, yr, yi, magb + (size_t)t*NBINS, twc, tws, lane, pr, pi);

        inv_accum(pr, pi, bz, tw0, tw1, tw2, wA, wB, lane, f, sa2);
    }
    __syncthreads();
    slot_store(Sw, b, bx, sacc[0], sacc[1], tid);
}

// ============================================================
// k_inv0s: iteration-0 istft from (mag, angles_init) -> slots
// ============================================================
__global__ __launch_bounds__(128,4) void k_inv0s(const float* __restrict__ mag,
                                                 const float* __restrict__ ang,
                                                 const float* __restrict__ win,
                                                 float* __restrict__ Sw){
    __shared__ __align__(16) float sacc[2][WSPAN];
    __shared__ __align__(16) float2 BZ[2][274];
    int tid = threadIdx.x, w = tid>>6, lane = tid&63;
    int b = blockIdx.y, bx = blockIdx.x;

    float2* bz = BZ[w];
    float2* sa2 = (float2*)sacc[w];

    Tw tw0 = twset((float)lane * (1.f/256.f));
    Tw tw1 = twset((float)(lane>>2) * (1.f/64.f));
    Tw tw2 = twset((float)(lane>>4) * (1.f/16.f));
    float twc[4], tws[4], wA[4], wB[4];
#pragma unroll
    for (int c=0;c<4;++c){
        int k = lane + 64*c;
        float x = (float)k * (1.f/512.f);
        twc[c]=cosr(x); tws[c]=sinr(x);
        float2 wv = ((const float2*)win)[k];
        wA[c]=wv.x; wB[c]=wv.y;
    }
#pragma unroll
    for (int j=0;j<8;++j){ int u = lane + 64*j; if (u < WSPAN/2) sa2[u]=make_float2(0.f,0.f); }
    __syncthreads();

    const float* magb = mag + ((size_t)b*TFRAMES)*NBINS;
    const float* angb = ang + ((size_t)b*TFRAMES)*NBINS;
    int t0 = (bx*2 + w)*FPW;

#pragma unroll 1
    for (int f=0; f<FPW; ++f){
        int t = t0 + f;
        const float* magp = magb + (size_t)t*NBINS;
        const float* angp = angb + (size_t)t*NBINS;
        float sr_[4], si_[4];
#pragma unroll
        for (int c=0;c<4;++c){
            int k = lane + 64*c;
            float m = magp[k], a = angp[k];
            float sn, cs;
            sincosf(a, &sn, &cs);
            sr_[c] = m*cs;
            si_[c] = (c==0 && lane==0) ? 0.f : m*sn;
        }
        // stage S (+Nyquist) for the c2r pack mirror (b64)
#pragma unroll
        for (int c=0;c<4;++c){ int k=lane+64*c; bz[P2(k)] = make_float2(sr_[c], si_[c]); }
        if (lane==0){
            bz[P2(256)] = make_float2(magp[256]*cosf(angp[256]), 0.f);
        }
        wsync();
        float pr[4], pi[4];
#pragma unroll
        for (int c=0;c<4;++c){
            int k = lane + 64*c;
            float2 yv = bz[P2(256-k)];
            float Aer = 0.5f*(sr_[c]+yv.x), Aei = 0.5f*(si_[c]-yv.y);
            float Er = sr_[c]-yv.x, Ei = si_[c]+yv.y;
            float Bor = 0.5f*(twc[c]*Er - tws[c]*Ei);
            float Boi = 0.5f*(twc[c]*Ei + tws[c]*Er);
            pr[c] = Aer - Boi;
            pi[c] = Aei + Bor;
        }
        wsync();
        inv_accum(pr, pi, bz, tw0, tw1, tw2, wA, wB, lane, f, sa2);
    }
    __syncthreads();
    slot_store(Sw, b, bx, sacc[0], sacc[1], tid);
}

// ============================================================
__global__ __launch_bounds__(128) void k_out(const float* __restrict__ S,
                                             const float* __restrict__ wsq,
                                             float* __restrict__ out){
    int b = blockIdx.y;
    int idx = blockIdx.x*128 + threadIdx.x;
    if (idx >= LOUT/2) return;
    const float* Sb = S + (size_t)b*SB;
    float2 v = xs2(Sb, wsq, 256 + 2*idx);
    ((float2*)(out + (size_t)b*LOUT))[idx] = v;
}

// ============================================================
extern "C" void kernel_launch(void* const* d_in, const int* in_sizes, int n_in,
                              void* d_out, int out_size, void* d_ws, size_t ws_size,
                              hipStream_t stream) {
    const float* mag  = (const float*)d_in[0];
    const float* ang0 = (const float*)d_in[1];
    const float* win  = (const float*)d_in[2];
    float* ws = (float*)d_ws;
    float* S[2] = { ws, ws + SBUF };
    float* wsqi = ws + 2*SBUF;
    float* outp = (float*)d_out;

    k_init<<<(XPLEN + 255)/256, 256, 0, stream>>>(win, wsqi);

    dim3 g(NBLK, BATCH);
    k_inv0s<<<g, 128, 0, stream>>>(mag, ang0, win, S[0]);
    for (int it = 0; it < NITER; ++it){
        k_gl<<<g, 128, 0, stream>>>(S[it%2], S[(it+1)%2], mag, win, wsqi);
    }
    k_out<<<dim3(640, BATCH), 128, 0, stream>>>(S[NITER%2], wsqi, outp);
}